// Round 10
// baseline (86.520 us; speedup 1.0000x reference)
//
#include <hip/hip_runtime.h>
#include <hip/hip_bf16.h>
#include <stdint.h>

typedef float f32x4 __attribute__((ext_vector_type(4)));
typedef short s16x8 __attribute__((ext_vector_type(8)));
typedef unsigned short u16;
typedef u16 u16x4 __attribute__((ext_vector_type(4)));

__device__ __align__(16) float g_tbl[16 * 256]; // 16 units x 64 lanes x f32x4

__device__ __forceinline__ u16 f2bf(float f) {
    union { __hip_bfloat16 h; u16 u; } cv;
    cv.h = __float2bfloat16(f);
    return cv.u;
}
__device__ __forceinline__ int pkbf(float lo, float hi) {
    return (int)(unsigned)f2bf(lo) | ((int)(unsigned)f2bf(hi) << 16);
}
__device__ __forceinline__ f32x4 mfma16(s16x8 a, s16x8 b, f32x4 c) {
    return __builtin_amdgcn_mfma_f32_16x16x32_bf16(a, b, c, 0, 0, 0);
}
__device__ __forceinline__ float exp2_hw(float x) {
    float r; asm("v_exp_f32 %0, %1" : "=v"(r) : "v"(x)); return r;
}
__device__ __forceinline__ int swz16(int v) {                 // lane^16 (verified R4-R9)
    return __builtin_amdgcn_ds_swizzle(v, 0x401F);
}
__device__ __forceinline__ int xor32i(int v, bool lo32) {     // lane^32 (verified R4-R9)
    auto r = __builtin_amdgcn_permlane32_swap(v, v, false, false);
    return lo32 ? r[1] : r[0];
}
__device__ __forceinline__ int pl_lo_to_hi(int v) {           // verified R5-R9
    auto r = __builtin_amdgcn_permlane32_swap(v, v, false, false);
    return r[0];
}
__device__ __forceinline__ s16x8 frag4(int d0, int d1, int d2, int d3) {
    union { int i[4]; s16x8 v; } u;
    u.i[0] = d0; u.i[1] = d1; u.i[2] = d2; u.i[3] = d3;
    return u.v;
}
#define C_FENCE() asm volatile("" ::: "memory")

// ---- one-block setup: per-lane fragment table (proven R8/R9) ----
__global__ void setup_kernel(
    const float* __restrict__ Wq, const float* __restrict__ bq,
    const float* __restrict__ Wk, const float* __restrict__ bk,
    const float* __restrict__ Wv, const float* __restrict__ bv,
    const float* __restrict__ Wo, const float* __restrict__ bo)
{
    const int lane = threadIdx.x & 63;
    if (threadIdx.x >= 64) return;
    const int c16 = lane & 15;
    const int g   = lane >> 4;
    const float qscale = 0.35355339059327373f * 1.4426950408889634f;

    f32x4* T = (f32x4*)g_tbl;
    union { s16x8 s; f32x4 f; } cv;
    #pragma unroll
    for (int j = 0; j < 6; ++j) {
        const float* Wsrc = (j < 2) ? Wq : (j < 4) ? Wk : Wv;
        const int colW = ((j & 1) << 4) | c16;
        const float sc = (j < 2) ? qscale : 1.0f;
        s16x8 wf;
        #pragma unroll
        for (int jj = 0; jj < 8; ++jj)
            wf[jj] = (short)f2bf(Wsrc[(g * 8 + jj) * 32 + colW] * sc);
        cv.s = wf;
        T[j * 64 + lane] = cv.f;
    }
    #pragma unroll
    for (int j2 = 0; j2 < 2; ++j2) {
        const int cout = j2 * 16 + c16;
        s16x8 wf;
        #pragma unroll
        for (int jj = 0; jj < 8; ++jj) {
            const int h = (g >> 1) * 2 + (jj >> 2);
            const int d = 4 * (g & 1) + (jj & 3);
            wf[jj] = (short)f2bf(Wo[(h * 8 + d) * 32 + cout]);
        }
        cv.s = wf;
        T[(6 + j2) * 64 + lane] = cv.f;
    }
    #pragma unroll
    for (int j = 0; j < 4; ++j) {
        const float* bsrc = (j < 2) ? bq : bk;
        const float sc = (j < 2) ? qscale : 1.0f;
        f32x4 b;
        #pragma unroll
        for (int i = 0; i < 4; ++i)
            b[i] = bsrc[((j & 1) << 4) + 4 * g + i] * sc;
        T[(8 + j) * 64 + lane] = b;
    }
    #pragma unroll
    for (int jv = 0; jv < 2; ++jv) {
        float b = bv[jv * 16 + c16];
        T[(12 + jv) * 64 + lane] = (f32x4){b, b, b, b};
    }
    #pragma unroll
    for (int j2 = 0; j2 < 2; ++j2) {
        f32x4 b;
        #pragma unroll
        for (int i = 0; i < 4; ++i)
            b[i] = bo[j2 * 16 + 4 * g + i];
        T[(14 + j2) * 64 + lane] = b;
    }
}

// 16 waves per block (forced residency: a workgroup launches atomically).
// 1 wave = 1 window (16 tokens), 4 windows/wave, grid 1024.
__global__ __launch_bounds__(1024) void swin_attn_kernel(
    const float* __restrict__ x, float* __restrict__ out)
{
    const int lane  = threadIdx.x & 63;
    const int wave  = threadIdx.x >> 6;     // 0..15
    const int c16   = lane & 15;
    const int g     = lane >> 4;
    const bool lo32 = (lane < 32);

    // per-wave staging; strides tuned for <=2-way bank aliasing, 16B-aligned rows
    __shared__ __align__(16) u16 qk[16][16][72]; // q 0..31 | gap | k 40..71 (row 144B)
    __shared__ __align__(16) u16 vT[16][32][24]; // [vslot][token] (row 48B)
    __shared__ __align__(16) u16 pb[16][16][24]; // [qt][kt]      (row 48B)
    __shared__ __align__(16) u16 zz[8];          // shared zero block (broadcast reads)

    if (threadIdx.x < 8) zz[threadIdx.x] = 0;
    __syncthreads(); // once; only barrier in the kernel

    // ---- prologue: 16 coalesced loads from fragment table (proven R8) ----
    const f32x4* T = (const f32x4*)g_tbl;
    f32x4 u[16];
    #pragma unroll
    for (int k = 0; k < 16; ++k) u[k] = T[k * 64 + lane];
    union { f32x4 f; s16x8 s; } cv;
    s16x8 wqkv[6], wo_frag[2];
    #pragma unroll
    for (int j = 0; j < 6; ++j) { cv.f = u[j]; wqkv[j] = cv.s; }
    cv.f = u[6]; wo_frag[0] = cv.s;
    cv.f = u[7]; wo_frag[1] = cv.s;
    f32x4 bias_qk[4] = {u[8], u[9], u[10], u[11]};
    f32x4 bias_v[2]  = {u[12], u[13]};
    f32x4 bo_frag[2] = {u[14], u[15]};

    const f32x4 zero4 = {0.f, 0.f, 0.f, 0.f};

    // hoisted fragment pointers; invalid lanes -> shared zero block (broadcast)
    const u16* ap_base = (g == 0) ? &qk[wave][c16][40] : &zz[0];
    const u16* bp_base = (g == 0) ? &qk[wave][c16][0]  : &zz[0];
    const int  hstep   = (g == 0) ? 8 : 0;
    const u16* pp      = (g < 2) ? &pb[wave][c16][g * 8] : &zz[0];
    const u16* vp_base = (g < 2) ? &vT[wave][c16 & 7][g * 8] : &zz[0];
    const int  vstep   = (g < 2) ? 8 * 24 : 0;

    // prologue: load window 0's x
    const int wbase = (blockIdx.x * 16 + wave) * 4;
    long curpix;
    f32x4 px0, px1;
    {
        const int w = wbase;
        const int b = w >> 14, rem = w & 16383, wi = rem >> 7, wj = rem & 127;
        const int row  = (wi * 4 + (c16 >> 2) + 2) & 511;
        const int colp = (wj * 4 + (c16 & 3) + 2) & 511;
        curpix = ((((long)b << 9) + row) * 512 + colp) * 32;
        px0 = *(const f32x4*)(x + curpix + g * 8);
        px1 = *(const f32x4*)(x + curpix + g * 8 + 4);
    }

    #pragma unroll 1
    for (int it = 0; it < 4; ++it) {
        const long pixbase = curpix;
        s16x8 xfrag = frag4(pkbf(px0[0], px0[1]), pkbf(px0[2], px0[3]),
                            pkbf(px1[0], px1[1]), pkbf(px1[2], px1[3]));

        // ---- phase A: projections -> LDS staging ----
        #pragma unroll
        for (int j = 0; j < 4; ++j) {     // q,k: C^T = W^T X^T (token-major)
            f32x4 c = mfma16(wqkv[j], xfrag, bias_qk[j]);
            const int col = (j < 2) ? (j * 16 + 4 * g) : (40 + (j - 2) * 16 + 4 * g);
            u16x4 qv;
            #pragma unroll
            for (int i = 0; i < 4; ++i) qv[i] = f2bf(c[i]);
            *(u16x4*)&qk[wave][c16][col] = qv;
        }
        #pragma unroll
        for (int jv = 0; jv < 2; ++jv) {  // v: C = X Wv (vslot-major)
            f32x4 c = mfma16(xfrag, wqkv[4 + jv], bias_v[jv]);
            u16x4 vv;
            #pragma unroll
            for (int i = 0; i < 4; ++i) vv[i] = f2bf(c[i]);
            *(u16x4*)&vT[wave][jv * 16 + c16][4 * g] = vv;
        }

        // prefetch next window's x (wrap at it==3: harmless re-read)
        {
            const int w = wbase + ((it + 1) & 3);
            const int b = w >> 14, rem = w & 16383, wi = rem >> 7, wj = rem & 127;
            const int row  = (wi * 4 + (c16 >> 2) + 2) & 511;
            const int colp = (wj * 4 + (c16 & 3) + 2) & 511;
            const long np = ((((long)b << 9) + row) * 512 + colp) * 32;
            px0 = *(const f32x4*)(x + np + g * 8);
            px1 = *(const f32x4*)(x + np + g * 8 + 4);
            curpix = np;
        }
        f32x4 r0 = *(const f32x4*)(x + pixbase + 4 * g);
        f32x4 r1 = *(const f32x4*)(x + pixbase + 16 + 4 * g);

        C_FENCE(); // staging writes -> fragment reads (in-order DS pipe)

        // ---- phase B: per head, scores + softmax + LDS-P + PV ----
        f32x4 o_acc[4];
        #pragma unroll
        for (int h = 0; h < 4; ++h) {
            s16x8 afrag = *(const s16x8*)(ap_base + h * hstep); // K_h[kt=c16][d] / zeros
            s16x8 bfrag = *(const s16x8*)(bp_base + h * hstep); // Q_h[qt=c16][d] / zeros
            f32x4 s = mfma16(afrag, bfrag, zero4); // S^T rows kt=4g+i, col qt=c16

            float e0 = exp2_hw(s[0]), e1 = exp2_hw(s[1]);
            float e2 = exp2_hw(s[2]), e3 = exp2_hw(s[3]);
            float part = (e0 + e1) + (e2 + e3);
            float sum  = part + __int_as_float(swz16(__float_as_int(part)));
            sum += __int_as_float(xor32i(__float_as_int(sum), lo32));
            const float inv = __builtin_amdgcn_rcpf(sum);
            u16x4 pv;
            pv[0] = f2bf(e0 * inv); pv[1] = f2bf(e1 * inv);
            pv[2] = f2bf(e2 * inv); pv[3] = f2bf(e3 * inv);
            *(u16x4*)&pb[wave][c16][4 * g] = pv; // [qt][kt]
            C_FENCE(); // P write -> P read

            s16x8 vfrag = *(const s16x8*)(vp_base + h * vstep); // V rows / zeros
            s16x8 pfrag = *(const s16x8*)pp;                    // P / zeros
            o_acc[h] = mfma16(vfrag, pfrag, zero4); // O_h rows d=4g+i (g<2), col qt=c16
            C_FENCE(); // P read before next head's P write
        }

        // ---- phase C: ofrag from registers (proven R5-R9) ----
        int t00 = pkbf(o_acc[0][0], o_acc[0][1]), t01 = pkbf(o_acc[0][2], o_acc[0][3]);
        int t10 = pkbf(o_acc[1][0], o_acc[1][1]), t11 = pkbf(o_acc[1][2], o_acc[1][3]);
        int t20 = pkbf(o_acc[2][0], o_acc[2][1]), t21 = pkbf(o_acc[2][2], o_acc[2][3]);
        int t30 = pkbf(o_acc[3][0], o_acc[3][1]), t31 = pkbf(o_acc[3][2], o_acc[3][3]);
        int m20 = pl_lo_to_hi(t20), m21 = pl_lo_to_hi(t21);
        int m30 = pl_lo_to_hi(t30), m31 = pl_lo_to_hi(t31);
        s16x8 ofrag = frag4(lo32 ? t00 : m20, lo32 ? t01 : m21,
                            lo32 ? t10 : m30, lo32 ? t11 : m31);

        // ---- out-proj + bias + residual + store ----
        f32x4 ci0 = bo_frag[0], ci1 = bo_frag[1];
        #pragma unroll
        for (int i = 0; i < 4; ++i) { ci0[i] += r0[i]; ci1[i] += r1[i]; }
        f32x4 c0 = mfma16(wo_frag[0], ofrag, ci0); // rows cout 4g+i, col token c16
        f32x4 c1 = mfma16(wo_frag[1], ofrag, ci1);
        *(f32x4*)(out + pixbase + 4 * g) = c0;
        *(f32x4*)(out + pixbase + 16 + 4 * g) = c1;

        C_FENCE(); // next window's staging after this window's reads
    }
}

extern "C" void kernel_launch(void* const* d_in, const int* in_sizes, int n_in,
                              void* d_out, int out_size, void* d_ws, size_t ws_size,
                              hipStream_t stream) {
    const float* x  = (const float*)d_in[0];
    const float* Wq = (const float*)d_in[1];
    const float* bq = (const float*)d_in[2];
    const float* Wk = (const float*)d_in[3];
    const float* bk = (const float*)d_in[4];
    const float* Wv = (const float*)d_in[5];
    const float* bv = (const float*)d_in[6];
    const float* Wo = (const float*)d_in[7];
    const float* bo = (const float*)d_in[8];
    float* out = (float*)d_out;

    hipLaunchKernelGGL(setup_kernel, dim3(1), dim3(64), 0, stream,
                       Wq, bq, Wk, bk, Wv, bv, Wo, bo);
    hipLaunchKernelGGL(swin_attn_kernel, dim3(1024), dim3(1024), 0, stream,
                       x, out);
}

// Round 11
// 76.379 us; speedup vs baseline: 1.1328x; 1.1328x over previous
//
#include <hip/hip_runtime.h>
#include <hip/hip_bf16.h>
#include <stdint.h>

typedef float f32x4 __attribute__((ext_vector_type(4)));
typedef float f32x16 __attribute__((ext_vector_type(16)));
typedef short s16x8 __attribute__((ext_vector_type(8)));
typedef unsigned short u16;
typedef u16 u16x4 __attribute__((ext_vector_type(4)));

__device__ __align__(16) float g_tbl[16 * 256]; // 16 units x 64 lanes x f32x4

__device__ __forceinline__ u16 f2bf(float f) {
    union { __hip_bfloat16 h; u16 u; } cv;
    cv.h = __float2bfloat16(f);
    return cv.u;
}
__device__ __forceinline__ int pkbf(float lo, float hi) {
    return (int)(unsigned)f2bf(lo) | ((int)(unsigned)f2bf(hi) << 16);
}
__device__ __forceinline__ f32x4 mfma16(s16x8 a, s16x8 b, f32x4 c) {
    return __builtin_amdgcn_mfma_f32_16x16x32_bf16(a, b, c, 0, 0, 0);
}
__device__ __forceinline__ f32x16 mfma32(s16x8 a, s16x8 b, f32x16 c) {
    return __builtin_amdgcn_mfma_f32_32x32x16_bf16(a, b, c, 0, 0, 0);
}
__device__ __forceinline__ float exp2_hw(float x) {
    float r; asm("v_exp_f32 %0, %1" : "=v"(r) : "v"(x)); return r;
}
__device__ __forceinline__ int xor32i(int v, bool lo32) {     // lane^32 (verified R4-R10)
    auto r = __builtin_amdgcn_permlane32_swap(v, v, false, false);
    return lo32 ? r[1] : r[0];
}
__device__ __forceinline__ s16x8 frag4(int d0, int d1, int d2, int d3) {
    union { int i[4]; s16x8 v; } u;
    u.i[0] = d0; u.i[1] = d1; u.i[2] = d2; u.i[3] = d3;
    return u.v;
}
#define C_FENCE() asm volatile("" ::: "memory")

// ---- one-block setup: per-lane fragment table (proven R8-R10) ----
__global__ void setup_kernel(
    const float* __restrict__ Wq, const float* __restrict__ bq,
    const float* __restrict__ Wk, const float* __restrict__ bk,
    const float* __restrict__ Wv, const float* __restrict__ bv,
    const float* __restrict__ Wo, const float* __restrict__ bo)
{
    const int lane = threadIdx.x & 63;
    if (threadIdx.x >= 64) return;
    const int c16 = lane & 15;
    const int g   = lane >> 4;
    const float qscale = 0.35355339059327373f * 1.4426950408889634f;

    f32x4* T = (f32x4*)g_tbl;
    union { s16x8 s; f32x4 f; } cv;
    #pragma unroll
    for (int j = 0; j < 6; ++j) {
        const float* Wsrc = (j < 2) ? Wq : (j < 4) ? Wk : Wv;
        const int colW = ((j & 1) << 4) | c16;
        const float sc = (j < 2) ? qscale : 1.0f;
        s16x8 wf;
        #pragma unroll
        for (int jj = 0; jj < 8; ++jj)
            wf[jj] = (short)f2bf(Wsrc[(g * 8 + jj) * 32 + colW] * sc);
        cv.s = wf;
        T[j * 64 + lane] = cv.f;
    }
    #pragma unroll
    for (int j2 = 0; j2 < 2; ++j2) {
        const int cout = j2 * 16 + c16;
        s16x8 wf;
        #pragma unroll
        for (int jj = 0; jj < 8; ++jj) {
            const int h = (g >> 1) * 2 + (jj >> 2);
            const int d = 4 * (g & 1) + (jj & 3);
            wf[jj] = (short)f2bf(Wo[(h * 8 + d) * 32 + cout]);
        }
        cv.s = wf;
        T[(6 + j2) * 64 + lane] = cv.f;
    }
    #pragma unroll
    for (int j = 0; j < 4; ++j) {
        const float* bsrc = (j < 2) ? bq : bk;
        const float sc = (j < 2) ? qscale : 1.0f;
        f32x4 b;
        #pragma unroll
        for (int i = 0; i < 4; ++i)
            b[i] = bsrc[((j & 1) << 4) + 4 * g + i] * sc;
        T[(8 + j) * 64 + lane] = b;
    }
    #pragma unroll
    for (int jv = 0; jv < 2; ++jv) {
        float b = bv[jv * 16 + c16];
        T[(12 + jv) * 64 + lane] = (f32x4){b, b, b, b};
    }
    #pragma unroll
    for (int j2 = 0; j2 < 2; ++j2) {
        f32x4 b;
        #pragma unroll
        for (int i = 0; i < 4; ++i)
            b[i] = bo[j2 * 16 + 4 * g + i];
        T[(14 + j2) * 64 + lane] = b;
    }
}

// 1 wave = 1 window, 4 waves/block, 4 windows/wave.
// 32x32x16 score+PV with kt-permutation pi = {0-3,8-11,4-7,12-15} (involution):
// P never leaves registers; heads fully independent; 3 fences/window.
__global__ __launch_bounds__(256) void swin_attn_kernel(
    const float* __restrict__ x, float* __restrict__ out)
{
    const int lane  = threadIdx.x & 63;
    const int wave  = threadIdx.x >> 6;
    const int c16   = lane & 15;
    const int g     = lane >> 4;
    const bool lo32 = (lane < 32);

    __shared__ __align__(16) u16 qk[4][16][72];  // [wave][token][q 0..31 | gap | k 40..71]
    __shared__ __align__(16) u16 vT[4][32][24];  // [wave][vslot h*8+d][token, pi order]
    __shared__ __align__(16) u16 ob[4][16][40];  // [wave][qt][32 slots + pad]
    __shared__ __align__(16) u16 zz[8];          // 16B zero block (broadcast reads)

    if (threadIdx.x < 8) zz[threadIdx.x] = 0;
    __syncthreads(); // only barrier

    // ---- prologue: 16 coalesced loads from fragment table (proven R8) ----
    const f32x4* T = (const f32x4*)g_tbl;
    f32x4 u[16];
    #pragma unroll
    for (int k = 0; k < 16; ++k) u[k] = T[k * 64 + lane];
    union { f32x4 f; s16x8 s; } cv;
    s16x8 wqkv[6], wo_frag[2];
    #pragma unroll
    for (int j = 0; j < 6; ++j) { cv.f = u[j]; wqkv[j] = cv.s; }
    cv.f = u[6]; wo_frag[0] = cv.s;
    cv.f = u[7]; wo_frag[1] = cv.s;
    f32x4 bias_qk[4] = {u[8], u[9], u[10], u[11]};
    f32x4 bias_v[2]  = {u[12], u[13]};
    f32x4 bo_frag[2] = {u[14], u[15]};

    f32x16 zero16;
    #pragma unroll
    for (int i = 0; i < 16; ++i) zero16[i] = 0.0f;

    // hoisted fragment pointers (invalid lanes -> zz broadcast)
    // score A (K): lane l holds row kt=l&31 (<16), k=d=(l>>5)*8+jj (<8) -> lanes 0-15 only
    const u16* kp = (lane < 16) ? &qk[wave][lane][40] : &zz[0];
    const u16* qp = (lane < 16) ? &qk[wave][lane][0]  : &zz[0];
    const int  kqstep = (lane < 16) ? 8 : 0;          // +h*8 u16
    // PV A (V): row vslot=h*8+(l&31) for (l&31)<8; k-slot jj -> token pi((l>>5)*8+jj)
    const u16* vp = ((lane & 31) < 8) ? &vT[wave][lane & 31][(lane >> 5) * 8] : &zz[0];
    const int  vstep = ((lane & 31) < 8) ? 8 * 24 : 0; // +h*8 rows

    // prologue: load window 0's x
    const int wbase = (blockIdx.x * 4 + wave) * 4;
    long curpix;
    f32x4 px0, px1;
    {
        const int w = wbase;
        const int b = w >> 14, rem = w & 16383, wi = rem >> 7, wj = rem & 127;
        const int row  = (wi * 4 + (c16 >> 2) + 2) & 511;
        const int colp = (wj * 4 + (c16 & 3) + 2) & 511;
        curpix = ((((long)b << 9) + row) * 512 + colp) * 32;
        px0 = *(const f32x4*)(x + curpix + g * 8);
        px1 = *(const f32x4*)(x + curpix + g * 8 + 4);
    }
    const int pi_g = (g == 1) ? 2 : (g == 2) ? 1 : g; // involution on quads

    #pragma unroll 1
    for (int it = 0; it < 4; ++it) {
        const long pixbase = curpix;
        s16x8 xfrag = frag4(pkbf(px0[0], px0[1]), pkbf(px0[2], px0[3]),
                            pkbf(px1[0], px1[1]), pkbf(px1[2], px1[3]));

        // ---- phase A: projections -> LDS staging ----
        #pragma unroll
        for (int j = 0; j < 4; ++j) {     // q,k: C^T = W^T X^T (token-major)
            f32x4 c = mfma16(wqkv[j], xfrag, bias_qk[j]);
            const int col = (j < 2) ? (j * 16 + 4 * g) : (40 + (j - 2) * 16 + 4 * g);
            u16x4 qv;
            #pragma unroll
            for (int i = 0; i < 4; ++i) qv[i] = f2bf(c[i]);
            *(u16x4*)&qk[wave][c16][col] = qv;
        }
        #pragma unroll
        for (int jv = 0; jv < 2; ++jv) {  // v: C = X Wv; store cols in pi order
            f32x4 c = mfma16(xfrag, wqkv[4 + jv], bias_v[jv]);
            u16x4 vv;
            #pragma unroll
            for (int i = 0; i < 4; ++i) vv[i] = f2bf(c[i]);
            *(u16x4*)&vT[wave][jv * 16 + c16][pi_g * 4] = vv;
        }

        // prefetch next window's x (wrap at it==3: harmless re-read)
        {
            const int w = wbase + ((it + 1) & 3);
            const int b = w >> 14, rem = w & 16383, wi = rem >> 7, wj = rem & 127;
            const int row  = (wi * 4 + (c16 >> 2) + 2) & 511;
            const int colp = (wj * 4 + (c16 & 3) + 2) & 511;
            const long np = ((((long)b << 9) + row) * 512 + colp) * 32;
            px0 = *(const f32x4*)(x + np + g * 8);
            px1 = *(const f32x4*)(x + np + g * 8 + 4);
            curpix = np;
        }
        f32x4 r0 = *(const f32x4*)(x + pixbase + 4 * g);
        f32x4 r1 = *(const f32x4*)(x + pixbase + 16 + 4 * g);

        C_FENCE(); // F1: staging complete before fragment reads

        // ---- phase B: 4 independent heads, register-only softmax/P ----
        int oA0[4], oA1[4]; // per head: pk(O[d0],O[d1]) and pk(O[d2],O[d3]) (lo: d0-3, hi: d4-7)
        #pragma unroll
        for (int h = 0; h < 4; ++h) {
            s16x8 kfrag = *(const s16x8*)(kp + h * kqstep); // K[kt=lane][d0-7] or zeros
            s16x8 qfrag = *(const s16x8*)(qp + h * kqstep); // Q[qt=lane][d0-7] or zeros
            f32x16 S = mfma32(kfrag, qfrag, zero16);
            // valid C-regs 0..7 = rows {0-3,8-11} lo / {4-7,12-15} hi = pi-ordered kt
            float e0 = exp2_hw(S[0]), e1 = exp2_hw(S[1]);
            float e2 = exp2_hw(S[2]), e3 = exp2_hw(S[3]);
            float e4 = exp2_hw(S[4]), e5 = exp2_hw(S[5]);
            float e6 = exp2_hw(S[6]), e7 = exp2_hw(S[7]);
            float sum = ((e0 + e1) + (e2 + e3)) + ((e4 + e5) + (e6 + e7));
            sum += __int_as_float(xor32i(__float_as_int(sum), lo32)); // other 8 kt
            const float inv = __builtin_amdgcn_rcpf(sum);
            // P B-frag: k-slot jj -> kt pi(...) = exactly C-reg order. Pure in-lane pack.
            s16x8 pfrag = frag4(pkbf(e0 * inv, e1 * inv), pkbf(e2 * inv, e3 * inv),
                                pkbf(e4 * inv, e5 * inv), pkbf(e6 * inv, e7 * inv));
            s16x8 vfrag = *(const s16x8*)(vp + h * vstep); // V rows d(<8) in pi cols
            f32x16 O = mfma32(vfrag, pfrag, zero16);
            // valid: rows 0-3 (+4 hi) = d0-3 / d4-7, col qt=l&31 (<16)
            oA0[h] = pkbf(O[0], O[1]);
            oA1[h] = pkbf(O[2], O[3]);
        }

        // ---- O -> ob staging (one round-trip per window) ----
        // word map w=0..15: h=(w>>2&1)+2*(w>>3), dpair=(w&1)+2*((w>>1)&1) pattern:
        // words 0-3:{h0d01,h0d23,h1d01,h1d23} 4-7: same d45/67 (hi lanes) 8-15: h2,h3
        if ((lane & 31) < 16) { // valid O lanes: c16 (lo, d0-3) and 32+c16 (hi, d4-7)
            const int wq = (lane >> 5) * 8; // u16 offset: lo words 0-3, hi words 4-7
            *(s16x8*)&ob[wave][c16][wq]      = frag4(oA0[0], oA1[0], oA0[1], oA1[1]);
            *(s16x8*)&ob[wave][c16][16 + wq] = frag4(oA0[2], oA1[2], oA0[3], oA1[3]);
        }
        C_FENCE(); // F2: ob writes before ofrag read

        // ofrag: B-frag slot (g,jj) -> word 4g..4g+3 (matches wo_frag k-map, R5-proven)
        s16x8 ofrag = *(const s16x8*)&ob[wave][c16][g * 8];

        // ---- out-proj + bias + residual + store ----
        f32x4 ci0 = bo_frag[0], ci1 = bo_frag[1];
        #pragma unroll
        for (int i = 0; i < 4; ++i) { ci0[i] += r0[i]; ci1[i] += r1[i]; }
        f32x4 c0 = mfma16(wo_frag[0], ofrag, ci0); // rows cout 4g+i, col token c16
        f32x4 c1 = mfma16(wo_frag[1], ofrag, ci1);
        *(f32x4*)(out + pixbase + 4 * g) = c0;
        *(f32x4*)(out + pixbase + 16 + 4 * g) = c1;

        C_FENCE(); // F3: this window's reads before next window's staging
    }
}

extern "C" void kernel_launch(void* const* d_in, const int* in_sizes, int n_in,
                              void* d_out, int out_size, void* d_ws, size_t ws_size,
                              hipStream_t stream) {
    const float* x  = (const float*)d_in[0];
    const float* Wq = (const float*)d_in[1];
    const float* bq = (const float*)d_in[2];
    const float* Wk = (const float*)d_in[3];
    const float* bk = (const float*)d_in[4];
    const float* Wv = (const float*)d_in[5];
    const float* bv = (const float*)d_in[6];
    const float* Wo = (const float*)d_in[7];
    const float* bo = (const float*)d_in[8];
    float* out = (float*)d_out;

    hipLaunchKernelGGL(setup_kernel, dim3(1), dim3(64), 0, stream,
                       Wq, bq, Wk, bk, Wv, bv, Wo, bo);
    hipLaunchKernelGGL(swin_attn_kernel, dim3(4096), dim3(256), 0, stream,
                       x, out);
}